// Round 9
// baseline (601.358 us; speedup 1.0000x reference)
//
#include <hip/hip_runtime.h>

// BLOOM attention block on MI355X (gfx950).
// GEMMs: proven 128x128 global_load_lds structure (~838 TF) with XCD-bijective
// block chunking (T1). 8-phase 256^2 abandoned (r3/r4/r6 regressions).
// Attention: flash w/ alibi+causal; 8 waves x 128 q-rows; K staged in LDS,
// V read DIRECT from L2 (m169: V-staging is overhead when KV L2-fits; XCD
// head-chunking keeps the 4-head KV working set ~4MB = per-XCD L2).
// exp2-domain softmax + defer-max rescale (T13), live-guard for masked tiles.

#define SEQL 2048
#define HIDN 4096
#define NHEAD 32
#define HDIM 128
#define H3 12288

typedef __bf16 bf16x8 __attribute__((ext_vector_type(8)));
typedef float f32x4 __attribute__((ext_vector_type(4)));
typedef unsigned short u16x8 __attribute__((ext_vector_type(8)));

__device__ __forceinline__ unsigned short f2bf(float f) {
  union { float f; unsigned u; } v; v.f = f;
  return (unsigned short)((v.u + 0x7FFFu + ((v.u >> 16) & 1u)) >> 16);
}

__device__ __forceinline__ void gload_lds16(const void* g, void* l) {
  __builtin_amdgcn_global_load_lds(
      (const __attribute__((address_space(1))) void*)g,
      (__attribute__((address_space(3))) void*)l, 16, 0, 0);
}

__global__ __launch_bounds__(256) void cvt_f32_bf16(
    const float* __restrict__ in, unsigned short* __restrict__ out, long long n) {
  long long i = ((long long)blockIdx.x * blockDim.x + threadIdx.x) * 8;
  long long stride = (long long)gridDim.x * blockDim.x * 8;
  for (; i < n; i += stride) {
    float4 a = *(const float4*)(in + i);
    float4 b = *(const float4*)(in + i + 4);
    u16x8 o;
    o[0] = f2bf(a.x); o[1] = f2bf(a.y); o[2] = f2bf(a.z); o[3] = f2bf(a.w);
    o[4] = f2bf(b.x); o[5] = f2bf(b.y); o[6] = f2bf(b.z); o[7] = f2bf(b.w);
    *(u16x8*)(out + i) = o;
  }
}

// C[M,N] = A[M,K] * B[N,K]^T (+ epilogue). 128x128 tile, BK=64, 4 waves,
// 16x16x32 MFMA. LDS[r][j16] = G[r][j16^(r&7)] via linear-dest gload_lds w/
// pre-swizzled source; reads XOR byte^((r&7)<<4). XCD-bijective 1-D grid.
// EPI==0: QKV scatter epilogue. EPI==1: +bias+residual, fp32 out.
template <int EPI>
__global__ __launch_bounds__(256) void gemm_nt(
    const unsigned short* __restrict__ A, const unsigned short* __restrict__ B,
    int M, int N, int K,
    const float* __restrict__ bias, const float* __restrict__ residual,
    float* __restrict__ outf,
    unsigned short* __restrict__ q_bf, unsigned short* __restrict__ k_bf,
    unsigned short* __restrict__ v_t) {
  __shared__ unsigned short As[128 * 64];
  __shared__ unsigned short Bs[128 * 64];

  const int tid = threadIdx.x;
  const int l = tid & 63;
  const int w = tid >> 6;
  const int wr = (w >> 1) * 64;
  const int wc = (w & 1) * 64;

  const int nb = gridDim.x;
  const int lin = (blockIdx.x & 7) * (nb >> 3) + (blockIdx.x >> 3);
  const int tm0 = (lin & 15) * 128;
  const int tn0 = (lin >> 4) * 128;

  const int lr = l >> 3;
  const int lc = (l & 7) ^ lr;

  f32x4 acc[4][4] = {};

  for (int kt = 0; kt < K; kt += 64) {
    __syncthreads();
#pragma unroll
    for (int i = 0; i < 4; ++i) {
      const int row = w * 32 + i * 8 + lr;
      gload_lds16(&A[(long long)(tm0 + row) * K + kt + lc * 8],
                  (char*)As + (w * 4 + i) * 1024);
      gload_lds16(&B[(long long)(tn0 + row) * K + kt + lc * 8],
                  (char*)Bs + (w * 4 + i) * 1024);
    }
    __syncthreads();
#pragma unroll
    for (int kk = 0; kk < 2; ++kk) {
      const int colb = kk * 64 + (l >> 4) * 16;
      bf16x8 af[4], bfr[4];
#pragma unroll
      for (int m = 0; m < 4; ++m) {
        int row = wr + m * 16 + (l & 15);
        af[m] = *(const bf16x8*)((char*)As + row * 128 + (colb ^ ((row & 7) << 4)));
      }
#pragma unroll
      for (int n = 0; n < 4; ++n) {
        int row = wc + n * 16 + (l & 15);
        bfr[n] = *(const bf16x8*)((char*)Bs + row * 128 + (colb ^ ((row & 7) << 4)));
      }
#pragma unroll
      for (int m = 0; m < 4; ++m)
#pragma unroll
        for (int n = 0; n < 4; ++n)
          acc[m][n] = __builtin_amdgcn_mfma_f32_16x16x32_bf16(af[m], bfr[n], acc[m][n], 0, 0, 0);
    }
  }

#pragma unroll
  for (int m = 0; m < 4; ++m) {
#pragma unroll
    for (int n = 0; n < 4; ++n) {
      const int col = tn0 + wc + n * 16 + (l & 15);
      const float bv = bias[col];
#pragma unroll
      for (int r = 0; r < 4; ++r) {
        const int rowg = tm0 + wr + m * 16 + (l >> 4) * 4 + r;
        float v = acc[m][n][r] + bv;
        if (EPI == 0) {
          const int head = col / 384;
          const int rem = col - head * 384;
          const int which = rem >> 7;
          const int d = rem & 127;
          const unsigned short bv16 = f2bf(v);
          if (which == 0)
            q_bf[(long long)(head * SEQL + rowg) * HDIM + d] = bv16;
          else if (which == 1)
            k_bf[(long long)(head * SEQL + rowg) * HDIM + d] = bv16;
          else
            v_t[(long long)(head * HDIM + d) * SEQL + rowg] = bv16;
        } else {
          const long long idx = (long long)rowg * N + col;
          outf[idx] = v + residual[idx];
        }
      }
    }
  }
}

// Flash attention with alibi + causal. 8 waves x 128 q-rows per block.
// Grid 512: xcd = b&7 owns heads [4c,4c+4); qtile (128 rows) longest-first.
// K staged in LDS (shared across waves); V fragments read DIRECT from L2
// (v_t layout [h][d][s] is exactly the PV B-operand V^T; per-lane 16B
// contiguous, 4 lanes/row -> full 64B lines). LDS 40KB.
__global__ __launch_bounds__(512) void attn_fwd(
    const unsigned short* __restrict__ q_bf, const unsigned short* __restrict__ k_bf,
    const unsigned short* __restrict__ v_t, const float* __restrict__ alibi,
    unsigned short* __restrict__ ctx_bf) {
  __shared__ unsigned short Ks[64 * 128];   // 16 KiB (rows = kv, 256B/row)
  __shared__ unsigned short Ps[8][16 * 64]; // 16 KiB (per-wave P tile)
  __shared__ float Al[SEQL];                // 8 KiB  (alibi*log2e)

  const int tid = threadIdx.x;
  const int l = tid & 63;
  const int w = tid >> 6;          // 0..7

  const float LOG2E = 1.4426950408889634f;

  const int b = blockIdx.x;
  const int i_ = b >> 3;
  const int h = (b & 7) * 4 + (i_ & 3);
  const int qtile = 15 - (i_ >> 2);
  const int qw = qtile * 128 + w * 16;  // this wave's q-row base

  for (int i = tid; i < SEQL; i += 512) Al[i] = alibi[h * SEQL + i] * LOG2E;

  // Q fragments: lane l holds row qw+(l&15), cols kk*32+(l>>4)*8..+7
  bf16x8 qf[4];
  {
    const unsigned short* qp =
        &q_bf[(long long)(h * SEQL + qw + (l & 15)) * HDIM + (l >> 4) * 8];
#pragma unroll
    for (int kk = 0; kk < 4; ++kk) qf[kk] = *(const bf16x8*)(qp + kk * 32);
  }

  // V direct-read base: row = n2*16 + (l&15) (d), col = kv0 + kk2*32 + (l>>4)*8
  const unsigned short* vB =
      v_t + (long long)(h * HDIM + (l & 15)) * SEQL + (l >> 4) * 8;

  f32x4 oacc[8] = {};
  float mrun[4] = {-__builtin_inff(), -__builtin_inff(), -__builtin_inff(), -__builtin_inff()};
  float lrun[4] = {0.f, 0.f, 0.f, 0.f};
  const float inv_norm2 = 0.08838834764831845f * 1.4426950408889634f;

  const int kR = l >> 4, kC = l & 15;

  const int ntiles = 2 * qtile + 2;  // causal: kv through qtile*128+127
  for (int t = 0; t < ntiles; ++t) {
    const int kv0 = t * 64;
    __syncthreads();
    // K staging split over 8 waves: 2 chunks/wave (1KB = 4 rows of 256B).
#pragma unroll
    for (int i = 0; i < 2; ++i) {
      const int kc = w * 2 + i;
      const int krow = kc * 4 + kR;
      const int ksrc = kC ^ ((i & 1) * 4 + kR);   // kc&1 == i&1
      gload_lds16(&k_bf[(long long)(h * SEQL + kv0 + krow) * HDIM + ksrc * 8],
                  (char*)Ks + kc * 1024);
    }
    __syncthreads();

    // Wave-uniform guard: fully-masked tile for this wave -> skip compute.
    if (kv0 <= qw + 15) {
      f32x4 sacc[4] = {};
#pragma unroll
      for (int kk = 0; kk < 4; ++kk) {
        const int colb = kk * 64 + (l >> 4) * 16;
#pragma unroll
        for (int n = 0; n < 4; ++n) {
          int row = n * 16 + (l & 15);
          bf16x8 kf = *(const bf16x8*)((char*)Ks + row * 256 + (colb ^ ((row & 7) << 4)));
          sacc[n] = __builtin_amdgcn_mfma_f32_16x16x32_bf16(qf[kk], kf, sacc[n], 0, 0, 0);
        }
      }

      float sc[4][4];
#pragma unroll
      for (int n = 0; n < 4; ++n) {
        const int kv = kv0 + n * 16 + (l & 15);
        const float al = Al[kv];
#pragma unroll
        for (int r = 0; r < 4; ++r) {
          const int qrow = qw + (l >> 4) * 4 + r;
          float v = al + inv_norm2 * sacc[n][r];
          sc[n][r] = (kv > qrow) ? -__builtin_inff() : v;
        }
      }

      // online softmax (exp2 domain) + defer-max (headroom 2^11)
#pragma unroll
      for (int r = 0; r < 4; ++r) {
        float m0 = fmaxf(fmaxf(sc[0][r], sc[1][r]), fmaxf(sc[2][r], sc[3][r]));
        m0 = fmaxf(m0, __shfl_xor(m0, 1, 64));
        m0 = fmaxf(m0, __shfl_xor(m0, 2, 64));
        m0 = fmaxf(m0, __shfl_xor(m0, 4, 64));
        m0 = fmaxf(m0, __shfl_xor(m0, 8, 64));
        if (__ballot(m0 > mrun[r] + 11.0f)) {
          const float mnew = fmaxf(mrun[r], m0);
          const float scale = exp2f(mrun[r] - mnew);
          mrun[r] = mnew;
          lrun[r] *= scale;
#pragma unroll
          for (int n2 = 0; n2 < 8; ++n2) oacc[n2][r] *= scale;
        }
        float p0 = 0.f;
#pragma unroll
        for (int n = 0; n < 4; ++n) {
          const float pv = exp2f(sc[n][r] - mrun[r]);
          sc[n][r] = pv;
          p0 += pv;
        }
        p0 += __shfl_xor(p0, 1, 64);
        p0 += __shfl_xor(p0, 2, 64);
        p0 += __shfl_xor(p0, 4, 64);
        p0 += __shfl_xor(p0, 8, 64);
        lrun[r] += p0;
      }

      // P -> per-wave LDS (bf16, swizzled) -> MFMA A fragments
#pragma unroll
      for (int n = 0; n < 4; ++n)
#pragma unroll
        for (int r = 0; r < 4; ++r) {
          const int row = (l >> 4) * 4 + r;
          const int colp = n * 16 + (l & 15);
          *(unsigned short*)((char*)Ps[w] + row * 128 + ((colp * 2) ^ ((row & 7) << 4))) =
              f2bf(sc[n][r]);
        }
      __threadfence_block();
      bf16x8 pf[2];
#pragma unroll
      for (int kk2 = 0; kk2 < 2; ++kk2) {
        const int row = l & 15;
        const int colb = kk2 * 64 + (l >> 4) * 16;
        pf[kk2] = *(const bf16x8*)((char*)Ps[w] + row * 128 + (colb ^ ((row & 7) << 4)));
      }

      // PV: ctx[16][128] += P[16][64] @ V[64][128]; V^T direct from L2.
#pragma unroll
      for (int n2 = 0; n2 < 8; ++n2) {
#pragma unroll
        for (int kk2 = 0; kk2 < 2; ++kk2) {
          bf16x8 vf = *(const bf16x8*)(vB + (long long)(n2 * 16) * SEQL +
                                       kv0 + kk2 * 32);
          oacc[n2] = __builtin_amdgcn_mfma_f32_16x16x32_bf16(pf[kk2], vf, oacc[n2], 0, 0, 0);
        }
      }
    }
  }

  // write ctx as bf16 [s][H], col = h*128 + d
#pragma unroll
  for (int n2 = 0; n2 < 8; ++n2)
#pragma unroll
    for (int r = 0; r < 4; ++r) {
      const int qrow = qw + (l >> 4) * 4 + r;
      const int col = h * HDIM + n2 * 16 + (l & 15);
      ctx_bf[(long long)qrow * HIDN + col] = f2bf(oacc[n2][r] / lrun[r]);
    }
}

extern "C" void kernel_launch(void* const* d_in, const int* in_sizes, int n_in,
                              void* d_out, int out_size, void* d_ws, size_t ws_size,
                              hipStream_t stream) {
  const float* hidden = (const float*)d_in[0];
  const float* residual = (const float*)d_in[1];
  const float* alibi = (const float*)d_in[2];
  // d_in[3]: attention_mask (bool) — causal mask computed analytically
  const float* Wqkv = (const float*)d_in[4];
  const float* bqkv = (const float*)d_in[5];
  const float* Wd = (const float*)d_in[6];
  const float* bd = (const float*)d_in[7];
  float* out = (float*)d_out;

  char* ws = (char*)d_ws;
  const size_t MB16 = 16777216;
  unsigned short* q_bf = (unsigned short*)(ws);
  unsigned short* k_bf = (unsigned short*)(ws + MB16);
  unsigned short* v_t = (unsigned short*)(ws + 2 * MB16);
  unsigned short* hid_bf = (unsigned short*)(ws + 3 * MB16);
  unsigned short* wqkv_bf = (unsigned short*)(ws + 4 * MB16);  // 96 MiB
  unsigned short* wd_bf = (unsigned short*)(ws + 4 * MB16);    // reuse after QKV GEMM
  unsigned short* ctx_bf = (unsigned short*)(ws + 4 * MB16 + 33554432);

  // 1. convert inputs to bf16
  cvt_f32_bf16<<<4096, 256, 0, stream>>>(hidden, hid_bf, (long long)SEQL * HIDN);
  cvt_f32_bf16<<<24576, 256, 0, stream>>>(Wqkv, wqkv_bf, (long long)H3 * HIDN);

  // 2. QKV projection (128^2, XCD-chunked) with interleaved-scatter epilogue
  gemm_nt<0><<<(SEQL / 128) * (H3 / 128), 256, 0, stream>>>(
      hid_bf, wqkv_bf, SEQL, H3, HIDN, bqkv, nullptr, nullptr, q_bf, k_bf, v_t);

  // 3. convert Wd (reuses Wqkv region — stream-ordered after QKV GEMM)
  cvt_f32_bf16<<<8192, 256, 0, stream>>>(Wd, wd_bf, (long long)HIDN * HIDN);

  // 4. flash attention: 8 waves x 128 q-rows, V direct from L2
  attn_fwd<<<NHEAD * (SEQL / 128), 512, 0, stream>>>(q_bf, k_bf, v_t, alibi, ctx_bf);

  // 5. output projection + bias + residual (fp32 out)
  gemm_nt<1><<<(SEQL / 128) * (HIDN / 128), 256, 0, stream>>>(
      ctx_bf, wd_bf, SEQL, HIDN, HIDN, bd, residual, out, nullptr, nullptr, nullptr);
}

// Round 10
// 506.841 us; speedup vs baseline: 1.1865x; 1.1865x over previous
//
#include <hip/hip_runtime.h>

// BLOOM attention block on MI355X (gfx950).
// GEMMs: proven 128x128 global_load_lds structure (~838 TF) with XCD-bijective
// block chunking (T1). 8-phase 256^2 abandoned (r3/r4/r6). V-direct-from-L2
// reverted (r9 regression +95us).
// Attention: flash w/ alibi+causal, 4 waves x 64 q-rows, DOUBLE-BUFFERED K/V
// LDS with raw s_barrier + counted vmcnt(8) (no compiler vmcnt(0) drain),
// exp2-domain softmax + defer-max (T13), live-guard, longest-first XCD map.

#define SEQL 2048
#define HIDN 4096
#define NHEAD 32
#define HDIM 128
#define H3 12288

typedef __bf16 bf16x8 __attribute__((ext_vector_type(8)));
typedef float f32x4 __attribute__((ext_vector_type(4)));
typedef unsigned short u16x8 __attribute__((ext_vector_type(8)));

__device__ __forceinline__ unsigned short f2bf(float f) {
  union { float f; unsigned u; } v; v.f = f;
  return (unsigned short)((v.u + 0x7FFFu + ((v.u >> 16) & 1u)) >> 16);
}

__device__ __forceinline__ void gload_lds16(const void* g, void* l) {
  __builtin_amdgcn_global_load_lds(
      (const __attribute__((address_space(1))) void*)g,
      (__attribute__((address_space(3))) void*)l, 16, 0, 0);
}

// raw barrier fenced against scheduler movement (rule #18 discipline)
#define BARX()                                  \
  do {                                          \
    __builtin_amdgcn_sched_barrier(0);          \
    __builtin_amdgcn_s_barrier();               \
    __builtin_amdgcn_sched_barrier(0);          \
  } while (0)
#define VMW(n) asm volatile("s_waitcnt vmcnt(" #n ")" ::: "memory")

__global__ __launch_bounds__(256) void cvt_f32_bf16(
    const float* __restrict__ in, unsigned short* __restrict__ out, long long n) {
  long long i = ((long long)blockIdx.x * blockDim.x + threadIdx.x) * 8;
  long long stride = (long long)gridDim.x * blockDim.x * 8;
  for (; i < n; i += stride) {
    float4 a = *(const float4*)(in + i);
    float4 b = *(const float4*)(in + i + 4);
    u16x8 o;
    o[0] = f2bf(a.x); o[1] = f2bf(a.y); o[2] = f2bf(a.z); o[3] = f2bf(a.w);
    o[4] = f2bf(b.x); o[5] = f2bf(b.y); o[6] = f2bf(b.z); o[7] = f2bf(b.w);
    *(u16x8*)(out + i) = o;
  }
}

// C[M,N] = A[M,K] * B[N,K]^T (+ epilogue). 128x128 tile, BK=64, 4 waves,
// 16x16x32 MFMA. LDS[r][j16] = G[r][j16^(r&7)] via linear-dest gload_lds w/
// pre-swizzled source; reads XOR byte^((r&7)<<4). XCD-bijective 1-D grid.
// EPI==0: QKV scatter epilogue. EPI==1: +bias+residual, fp32 out.
template <int EPI>
__global__ __launch_bounds__(256) void gemm_nt(
    const unsigned short* __restrict__ A, const unsigned short* __restrict__ B,
    int M, int N, int K,
    const float* __restrict__ bias, const float* __restrict__ residual,
    float* __restrict__ outf,
    unsigned short* __restrict__ q_bf, unsigned short* __restrict__ k_bf,
    unsigned short* __restrict__ v_t) {
  __shared__ unsigned short As[128 * 64];
  __shared__ unsigned short Bs[128 * 64];

  const int tid = threadIdx.x;
  const int l = tid & 63;
  const int w = tid >> 6;
  const int wr = (w >> 1) * 64;
  const int wc = (w & 1) * 64;

  const int nb = gridDim.x;
  const int lin = (blockIdx.x & 7) * (nb >> 3) + (blockIdx.x >> 3);
  const int tm0 = (lin & 15) * 128;
  const int tn0 = (lin >> 4) * 128;

  const int lr = l >> 3;
  const int lc = (l & 7) ^ lr;

  f32x4 acc[4][4] = {};

  for (int kt = 0; kt < K; kt += 64) {
    __syncthreads();
#pragma unroll
    for (int i = 0; i < 4; ++i) {
      const int row = w * 32 + i * 8 + lr;
      gload_lds16(&A[(long long)(tm0 + row) * K + kt + lc * 8],
                  (char*)As + (w * 4 + i) * 1024);
      gload_lds16(&B[(long long)(tn0 + row) * K + kt + lc * 8],
                  (char*)Bs + (w * 4 + i) * 1024);
    }
    __syncthreads();
#pragma unroll
    for (int kk = 0; kk < 2; ++kk) {
      const int colb = kk * 64 + (l >> 4) * 16;
      bf16x8 af[4], bfr[4];
#pragma unroll
      for (int m = 0; m < 4; ++m) {
        int row = wr + m * 16 + (l & 15);
        af[m] = *(const bf16x8*)((char*)As + row * 128 + (colb ^ ((row & 7) << 4)));
      }
#pragma unroll
      for (int n = 0; n < 4; ++n) {
        int row = wc + n * 16 + (l & 15);
        bfr[n] = *(const bf16x8*)((char*)Bs + row * 128 + (colb ^ ((row & 7) << 4)));
      }
#pragma unroll
      for (int m = 0; m < 4; ++m)
#pragma unroll
        for (int n = 0; n < 4; ++n)
          acc[m][n] = __builtin_amdgcn_mfma_f32_16x16x32_bf16(af[m], bfr[n], acc[m][n], 0, 0, 0);
    }
  }

#pragma unroll
  for (int m = 0; m < 4; ++m) {
#pragma unroll
    for (int n = 0; n < 4; ++n) {
      const int col = tn0 + wc + n * 16 + (l & 15);
      const float bv = bias[col];
#pragma unroll
      for (int r = 0; r < 4; ++r) {
        const int rowg = tm0 + wr + m * 16 + (l >> 4) * 4 + r;
        float v = acc[m][n][r] + bv;
        if (EPI == 0) {
          const int head = col / 384;
          const int rem = col - head * 384;
          const int which = rem >> 7;
          const int d = rem & 127;
          const unsigned short bv16 = f2bf(v);
          if (which == 0)
            q_bf[(long long)(head * SEQL + rowg) * HDIM + d] = bv16;
          else if (which == 1)
            k_bf[(long long)(head * SEQL + rowg) * HDIM + d] = bv16;
          else
            v_t[(long long)(head * HDIM + d) * SEQL + rowg] = bv16;
        } else {
          const long long idx = (long long)rowg * N + col;
          outf[idx] = v + residual[idx];
        }
      }
    }
  }
}

// Flash attention, alibi + causal. 4 waves x 64 q-rows, KV tiles of 64.
// Double-buffered K/V LDS: stage tile t+1 at loop top (WAR-safe: end-of-iter
// barrier separates last read of that buffer), counted vmcnt(8) confirms
// tile t (8 DMA ops/wave, in-order retirement), raw s_barrier (no drain).
// Grid 1024: xcd = b&7 owns heads [4c,4c+4); qtiles longest-first. LDS 80KB.
__global__ __launch_bounds__(256) void attn_fwd(
    const unsigned short* __restrict__ q_bf, const unsigned short* __restrict__ k_bf,
    const unsigned short* __restrict__ v_t, const float* __restrict__ alibi,
    unsigned short* __restrict__ ctx_bf) {
  __shared__ unsigned short Ks[2][64 * 128];  // 32 KiB (rows = kv, 256B/row)
  __shared__ unsigned short Vs[2][128 * 64];  // 32 KiB (rows = d, 128B/row)
  __shared__ unsigned short Ps[4][16 * 64];   // 8 KiB  (per-wave P tile)
  __shared__ float Al[SEQL];                  // 8 KiB  (alibi*log2e)

  const int tid = threadIdx.x;
  const int l = tid & 63;
  const int w = tid >> 6;

  const float LOG2E = 1.4426950408889634f;

  const int b = blockIdx.x;
  const int i_ = b >> 3;
  const int h = (b & 7) * 4 + (i_ & 3);
  const int qtile = 31 - (i_ >> 2);
  const int qw = qtile * 64 + w * 16;
  const int ntiles = qtile + 1;

  const int alN = ntiles * 64;  // only the causal prefix is ever read
  for (int i = tid; i < alN; i += 256) Al[i] = alibi[h * SEQL + i] * LOG2E;
  asm volatile("s_waitcnt lgkmcnt(0)" ::: "memory");  // my Al writes done

  bf16x8 qf[4];
  {
    const unsigned short* qp =
        &q_bf[(long long)(h * SEQL + qw + (l & 15)) * HDIM + (l >> 4) * 8];
#pragma unroll
    for (int kk = 0; kk < 4; ++kk) qf[kk] = *(const bf16x8*)(qp + kk * 32);
  }

  f32x4 oacc[8] = {};
  float mrun[4] = {-__builtin_inff(), -__builtin_inff(), -__builtin_inff(), -__builtin_inff()};
  float lrun[4] = {0.f, 0.f, 0.f, 0.f};
  const float inv_norm2 = 0.08838834764831845f * 1.4426950408889634f;

  const int kR = l >> 4, kC = l & 15;
  const int vR = l >> 3, vC = (l & 7) ^ vR;

  // Stage tile t into buf t&1: 4 K-chunks + 4 V-chunks per wave = 8 DMA ops.
  auto stage = [&](int t) {
    const int buf = t & 1;
    const int kv0 = t * 64;
#pragma unroll
    for (int i = 0; i < 4; ++i) {
      const int c = w * 4 + i;
      const int krow = c * 4 + kR;                 // row&7 = (i&1)*4 + kR
      const int ksrc = kC ^ ((i & 1) * 4 + kR);
      gload_lds16(&k_bf[(long long)(h * SEQL + kv0 + krow) * HDIM + ksrc * 8],
                  (char*)Ks[buf] + c * 1024);
      const int vrow = c * 8 + vR;                 // row&7 = vR
      gload_lds16(&v_t[(long long)(h * HDIM + vrow) * SEQL + kv0 + vC * 8],
                  (char*)Vs[buf] + c * 1024);
    }
  };

  stage(0);
  for (int t = 0; t < ntiles; ++t) {
    const int cur = t & 1;
    const int kv0 = t * 64;
    const bool g = (t + 1) < ntiles;
    if (g) stage(t + 1);                 // into buf^1 (last read ended at
                                         // previous end-of-iter barrier)
    if (g) { VMW(8); } else { VMW(0); }  // confirm tile t's 8 DMA ops
    BARX();                              // all waves' tile-t writes visible

    if (kv0 <= qw + 15) {                // wave-uniform live guard
      f32x4 sacc[4] = {};
#pragma unroll
      for (int kk = 0; kk < 4; ++kk) {
        const int colb = kk * 64 + (l >> 4) * 16;
#pragma unroll
        for (int n = 0; n < 4; ++n) {
          int row = n * 16 + (l & 15);
          bf16x8 kf = *(const bf16x8*)((char*)Ks[cur] + row * 256 +
                                       (colb ^ ((row & 7) << 4)));
          sacc[n] = __builtin_amdgcn_mfma_f32_16x16x32_bf16(qf[kk], kf, sacc[n], 0, 0, 0);
        }
      }

      float sc[4][4];
#pragma unroll
      for (int n = 0; n < 4; ++n) {
        const int kv = kv0 + n * 16 + (l & 15);
        const float al = Al[kv];
#pragma unroll
        for (int r = 0; r < 4; ++r) {
          const int qrow = qw + (l >> 4) * 4 + r;
          float v = al + inv_norm2 * sacc[n][r];
          sc[n][r] = (kv > qrow) ? -__builtin_inff() : v;
        }
      }

      // online softmax (exp2 domain) + defer-max (headroom 2^11)
#pragma unroll
      for (int r = 0; r < 4; ++r) {
        float m0 = fmaxf(fmaxf(sc[0][r], sc[1][r]), fmaxf(sc[2][r], sc[3][r]));
        m0 = fmaxf(m0, __shfl_xor(m0, 1, 64));
        m0 = fmaxf(m0, __shfl_xor(m0, 2, 64));
        m0 = fmaxf(m0, __shfl_xor(m0, 4, 64));
        m0 = fmaxf(m0, __shfl_xor(m0, 8, 64));
        if (__ballot(m0 > mrun[r] + 11.0f)) {
          const float mnew = fmaxf(mrun[r], m0);
          const float scale = exp2f(mrun[r] - mnew);
          mrun[r] = mnew;
          lrun[r] *= scale;
#pragma unroll
          for (int n2 = 0; n2 < 8; ++n2) oacc[n2][r] *= scale;
        }
        float p0 = 0.f;
#pragma unroll
        for (int n = 0; n < 4; ++n) {
          const float pv = exp2f(sc[n][r] - mrun[r]);
          sc[n][r] = pv;
          p0 += pv;
        }
        p0 += __shfl_xor(p0, 1, 64);
        p0 += __shfl_xor(p0, 2, 64);
        p0 += __shfl_xor(p0, 4, 64);
        p0 += __shfl_xor(p0, 8, 64);
        lrun[r] += p0;
      }

      // P -> per-wave LDS (bf16, swizzled) -> MFMA A fragments
#pragma unroll
      for (int n = 0; n < 4; ++n)
#pragma unroll
        for (int r = 0; r < 4; ++r) {
          const int row = (l >> 4) * 4 + r;
          const int colp = n * 16 + (l & 15);
          *(unsigned short*)((char*)Ps[w] + row * 128 + ((colp * 2) ^ ((row & 7) << 4))) =
              f2bf(sc[n][r]);
        }
      __threadfence_block();
      bf16x8 pf[2];
#pragma unroll
      for (int kk2 = 0; kk2 < 2; ++kk2) {
        const int row = l & 15;
        const int colb = kk2 * 64 + (l >> 4) * 16;
        pf[kk2] = *(const bf16x8*)((char*)Ps[w] + row * 128 + (colb ^ ((row & 7) << 4)));
      }

      // PV: ctx[16][128] += P[16][64] @ V[64][128]
#pragma unroll
      for (int n2 = 0; n2 < 8; ++n2) {
#pragma unroll
        for (int kk2 = 0; kk2 < 2; ++kk2) {
          const int row = n2 * 16 + (l & 15);
          const int colb = kk2 * 64 + (l >> 4) * 16;
          bf16x8 vf = *(const bf16x8*)((char*)Vs[cur] + row * 128 +
                                       (colb ^ ((row & 7) << 4)));
          oacc[n2] = __builtin_amdgcn_mfma_f32_16x16x32_bf16(pf[kk2], vf, oacc[n2], 0, 0, 0);
        }
      }
    }
    BARX();  // all waves done reading buf[cur]; next iter overwrites it
  }

  // write ctx as bf16 [s][H], col = h*128 + d
#pragma unroll
  for (int n2 = 0; n2 < 8; ++n2)
#pragma unroll
    for (int r = 0; r < 4; ++r) {
      const int qrow = qw + (l >> 4) * 4 + r;
      const int col = h * HDIM + n2 * 16 + (l & 15);
      ctx_bf[(long long)qrow * HIDN + col] = f2bf(oacc[n2][r] / lrun[r]);
    }
}

extern "C" void kernel_launch(void* const* d_in, const int* in_sizes, int n_in,
                              void* d_out, int out_size, void* d_ws, size_t ws_size,
                              hipStream_t stream) {
  const float* hidden = (const float*)d_in[0];
  const float* residual = (const float*)d_in[1];
  const float* alibi = (const float*)d_in[2];
  // d_in[3]: attention_mask (bool) — causal mask computed analytically
  const float* Wqkv = (const float*)d_in[4];
  const float* bqkv = (const float*)d_in[5];
  const float* Wd = (const float*)d_in[6];
  const float* bd = (const float*)d_in[7];
  float* out = (float*)d_out;

  char* ws = (char*)d_ws;
  const size_t MB16 = 16777216;
  unsigned short* q_bf = (unsigned short*)(ws);
  unsigned short* k_bf = (unsigned short*)(ws + MB16);
  unsigned short* v_t = (unsigned short*)(ws + 2 * MB16);
  unsigned short* hid_bf = (unsigned short*)(ws + 3 * MB16);
  unsigned short* wqkv_bf = (unsigned short*)(ws + 4 * MB16);  // 96 MiB
  unsigned short* wd_bf = (unsigned short*)(ws + 4 * MB16);    // reuse after QKV GEMM
  unsigned short* ctx_bf = (unsigned short*)(ws + 4 * MB16 + 33554432);

  // 1. convert inputs to bf16
  cvt_f32_bf16<<<4096, 256, 0, stream>>>(hidden, hid_bf, (long long)SEQL * HIDN);
  cvt_f32_bf16<<<24576, 256, 0, stream>>>(Wqkv, wqkv_bf, (long long)H3 * HIDN);

  // 2. QKV projection (128^2, XCD-chunked) with interleaved-scatter epilogue
  gemm_nt<0><<<(SEQL / 128) * (H3 / 128), 256, 0, stream>>>(
      hid_bf, wqkv_bf, SEQL, H3, HIDN, bqkv, nullptr, nullptr, q_bf, k_bf, v_t);

  // 3. convert Wd (reuses Wqkv region — stream-ordered after QKV GEMM)
  cvt_f32_bf16<<<8192, 256, 0, stream>>>(Wd, wd_bf, (long long)HIDN * HIDN);

  // 4. flash attention: dbuf K/V + counted vmcnt, longest-first + XCD chunk
  attn_fwd<<<NHEAD * (SEQL / 64), 256, 0, stream>>>(q_bf, k_bf, v_t, alibi, ctx_bf);

  // 5. output projection + bias + residual (fp32 out)
  gemm_nt<1><<<(SEQL / 128) * (HIDN / 128), 256, 0, stream>>>(
      ctx_bf, wd_bf, SEQL, HIDN, HIDN, bd, residual, out, nullptr, nullptr, nullptr);
}